// Round 9
// baseline (929.458 us; speedup 1.0000x reference)
//
#include <hip/hip_runtime.h>
#include <math.h>

// Problem constants (NaViT encoder)
#define LNUM 2
#define BB   4
#define NN   2048
#define DIM  768
#define NH   12
#define DH   64
#define MLPD 3072
#define QKVD 2304   // fused q|k|v row stride

typedef __attribute__((ext_vector_type(8))) short bf16x8;
typedef __attribute__((ext_vector_type(4))) float f32x4;
typedef unsigned short ushort_t;

__device__ __forceinline__ ushort_t f2bf(float f) {
    union { float f; unsigned u; } v; v.f = f;
    unsigned r = v.u + 0x7fff + ((v.u >> 16) & 1);  // RNE
    return (ushort_t)(r >> 16);
}
__device__ __forceinline__ float bf2f(ushort_t s) {
    union { unsigned u; float f; } v; v.u = ((unsigned)s) << 16;
    return v.f;
}
__device__ __forceinline__ void gld16(const void* g, void* l) {
    __builtin_amdgcn_global_load_lds(
        (const __attribute__((address_space(1))) void*)g,
        (__attribute__((address_space(3))) void*)l, 16, 0, 0);
}
// tanh-form GELU (max |err| vs exact erf-GELU ~3e-4 — invisible at bf16)
__device__ __forceinline__ float gelu_f(float x) {
    const float y = 0.7978845608028654f * (x + 0.044715f * x * x * x);
    const float t = 1.f - 2.f / (1.f + __expf(2.f * y));  // tanh(y), inf-safe
    return 0.5f * x * (1.f + t);
}

// ---------------------------------------------------------------------------
// Fused weight convert+transpose for ALL weights in ONE launch (was 11
// dispatches). Each block does one 32x32 tile; compile-time range table maps
// blockIdx -> (src, dst, K, N). W fp32 [K,N] -> Wt bf16 [N,K].
// ---------------------------------------------------------------------------
#define WOFF_L 7077888
__global__ __launch_bounds__(256) void wconvert_all_kernel(
    const float* __restrict__ peW, const float* __restrict__ Wq,
    const float* __restrict__ Wkv, const float* __restrict__ Wo,
    const float* __restrict__ W1, const float* __restrict__ W2,
    ushort_t* __restrict__ wbf)
{
    int bid = blockIdx.x;
    const float* src; ushort_t* dst; int K, N;
    // per-layer tile counts: Wq 576, Wkv 1152, Wo 576, W1 2304, W2 2304 = 6912
    if (bid < 576)        { src = peW;                      dst = wbf;                               K = 768;  N = 768;  }
    else {
        bid -= 576;
        const int layer = bid / 6912;
        int t = bid % 6912;
        const size_t lw = (size_t)layer * WOFF_L;
        if (t < 576)        {           src = Wq  + (size_t)layer * 768 * 768;   dst = wbf + 589824 + lw;           K = 768;  N = 768;  }
        else if (t < 1728)  { t -= 576; src = Wkv + (size_t)layer * 768 * 1536;  dst = wbf + 589824 + 589824 + lw;  K = 768;  N = 1536; }
        else if (t < 2304)  { t -= 1728; src = Wo + (size_t)layer * 768 * 768;   dst = wbf + 589824 + 1769472 + lw; K = 768;  N = 768;  }
        else if (t < 4608)  { t -= 2304; src = W1 + (size_t)layer * 768 * 3072;  dst = wbf + 589824 + 2359296 + lw; K = 768;  N = 3072; }
        else                { t -= 4608; src = W2 + (size_t)layer * 3072 * 768;  dst = wbf + 589824 + 4718592 + lw; K = 3072; N = 768;  }
        bid = t;
    }
    const int tilesN = N / 32;
    const int nt = (bid % tilesN) * 32, kt = (bid / tilesN) * 32;

    __shared__ ushort_t tl[32][33];
    const int tx = threadIdx.x & 31, ty = threadIdx.x >> 5;  // ty 0..7
#pragma unroll
    for (int r = 0; r < 4; r++) {
        const int k = kt + ty + r * 8;
        tl[ty + r * 8][tx] = f2bf(src[(size_t)k * N + nt + tx]);
    }
    __syncthreads();
#pragma unroll
    for (int r = 0; r < 4; r++) {
        const int n = nt + ty + r * 8;
        dst[(size_t)n * K + kt + tx] = tl[tx][ty + r * 8];
    }
}

// ---------------------------------------------------------------------------
// LayerNorm over last dim (768). One block (192 thr = 3 waves) per row;
// each thread owns 4 consecutive floats: ONE dwordx4 load + ONE 8B packed
// store (r9, G13 — was 3 scalar loads + 3 scalar stores). OT: float|ushort
// ---------------------------------------------------------------------------
template <typename OT>
__global__ __launch_bounds__(192) void ln_kernel(const float* in, const float* g, OT* out)
{
    const int row = blockIdx.x;
    const int tid = threadIdx.x;
    const float4 v = *(const float4*)(in + (size_t)row * DIM + tid * 4);
    float s  = (v.x + v.y) + (v.z + v.w);
    float s2 = (v.x * v.x + v.y * v.y) + (v.z * v.z + v.w * v.w);
#pragma unroll
    for (int o = 32; o; o >>= 1) {
        s  += __shfl_xor(s, o);
        s2 += __shfl_xor(s2, o);
    }
    __shared__ float red[6];
    const int wid = tid >> 6;  // 0..2
    if ((tid & 63) == 0) { red[wid] = s; red[wid + 3] = s2; }
    __syncthreads();
    s  = red[0] + red[1] + red[2];
    s2 = red[3] + red[4] + red[5];
    const float mean = s * (1.f / DIM);
    const float var  = s2 * (1.f / DIM) - mean * mean;
    const float inv  = rsqrtf(var + 1e-5f);
    const float4 gv = *(const float4*)(g + tid * 4);
    const float o0 = (v.x - mean) * inv * gv.x;
    const float o1 = (v.y - mean) * inv * gv.y;
    const float o2 = (v.z - mean) * inv * gv.z;
    const float o3 = (v.w - mean) * inv * gv.w;
    if constexpr (sizeof(OT) == 2) {
        const unsigned lo = (unsigned)f2bf(o0) | ((unsigned)f2bf(o1) << 16);
        const unsigned hi = (unsigned)f2bf(o2) | ((unsigned)f2bf(o3) << 16);
        *(uint2*)((ushort_t*)out + (size_t)row * DIM + tid * 4) = make_uint2(lo, hi);
    } else {
        *(float4*)((float*)out + (size_t)row * DIM + tid * 4) = make_float4(o0, o1, o2, o3);
    }
}

// ---------------------------------------------------------------------------
// BF16 MFMA GEMM: C[M,N] = act(A[M,K] @ Bt[N,K]^T + bias) + resid
// TM x 128 tile, BK=64, 256 thr = 4 waves (2x2), 16x16x32 MFMA.
// Staging swizzle: 8 lanes/row (128B), chunk ^= row&7 -> conflict-free
// fragment reads (SQ_LDS_BANK_CONFLICT = 0 measured).
//
// r8 structure: dbuf + counted s_waitcnt vmcnt(NL) + raw s_barrier (T3+T4).
// r8 post-mortem: W1 (TM=128, K=768) flat at ~100 us across three sync
// structures -> binder is staged-bytes-per-FLOP vs per-CU L2 share at
// 2 blocks/CU (64 KB per K-step-pair ~= fair-share L2 BW), not the schedule.
// TM choice: r9 moves W2 to TM=128 (staging intensity 131 vs 44 FLOP/B;
// 384 blocks @ 2/CU = 75% fill; K=3072 amortizes best). pe/Wo stay TM=64
// (r4 regression context) pending W2's A/B verdict.
// ---------------------------------------------------------------------------
template <int TM>
__global__ __launch_bounds__(256) void gemm_bf(
    const ushort_t* __restrict__ A, const ushort_t* __restrict__ Bt,
    const float* __restrict__ bias, const float* __restrict__ resid,
    void* __restrict__ Cv, int M, int N, int K, int outbf, int act)
{
    constexpr int MF = TM / 32;  // m-frags per wave: 4 (TM=128) or 2 (TM=64)
    constexpr int AG = TM / 32;  // A staging groups of 32 rows
    __shared__ ushort_t As[2][TM * 64];
    __shared__ ushort_t Bs[2][128 * 64];
    const int tid  = threadIdx.x;
    const int w    = tid >> 6, lane = tid & 63;
    const int lq   = lane & 15, quad = lane >> 4;
    const int wm   = w & 1, wn = w >> 1;
    const int tileM = blockIdx.y * TM, tileN = blockIdx.x * 128;

    // staging coords: row-within-group = w*8 + (lane>>3); chunk = (lane&7)^srow
    const int srow   = lane >> 3;                 // 0..7
    const int schunk = (lane & 7) ^ srow;         // swizzled k-chunk (8 ushorts)
    const ushort_t* agp[AG];
    const ushort_t* bgp[4];
#pragma unroll
    for (int g = 0; g < AG; g++)
        agp[g] = A + (size_t)(tileM + g * 32 + w * 8 + srow) * K + schunk * 8;
#pragma unroll
    for (int g = 0; g < 4; g++)
        bgp[g] = Bt + (size_t)(tileN + g * 32 + w * 8 + srow) * K + schunk * 8;

    f32x4 acc[MF][4];
#pragma unroll
    for (int m = 0; m < MF; m++)
#pragma unroll
        for (int n = 0; n < 4; n++) acc[m][n] = (f32x4){0.f, 0.f, 0.f, 0.f};

    const int fsw0 = (quad ^ (lq & 7)) * 8;       // chunk quad   slot offset
    const int fsw1 = ((quad ^ (lq & 7)) ^ 4) * 8; // chunk quad+4 slot offset

    // prologue: stage tile 0 into buf 0 (NL loads in flight)
#pragma unroll
    for (int g = 0; g < AG; g++)
        gld16(agp[g], As[0] + (g * 32 + w * 8) * 64);
#pragma unroll
    for (int g = 0; g < 4; g++)
        gld16(bgp[g], Bs[0] + (g * 32 + w * 8) * 64);

    int buf = 0;
    for (int kt = 0; kt < K; kt += 64, buf ^= 1) {
        if (kt + 64 < K) {
            // stage NEXT tile into the other buffer (issue-only)
#pragma unroll
            for (int g = 0; g < AG; g++)
                gld16(agp[g] + kt + 64, As[buf ^ 1] + (g * 32 + w * 8) * 64);
#pragma unroll
            for (int g = 0; g < 4; g++)
                gld16(bgp[g] + kt + 64, Bs[buf ^ 1] + (g * 32 + w * 8) * 64);
            // wait for TILE t's loads only; tile t+1's NL loads stay in flight
            if constexpr (TM == 128) asm volatile("s_waitcnt vmcnt(8)" ::: "memory");
            else                     asm volatile("s_waitcnt vmcnt(6)" ::: "memory");
        } else {
            asm volatile("s_waitcnt vmcnt(0)" ::: "memory");
        }
        __builtin_amdgcn_s_barrier();   // raw: no compiler vmcnt(0) drain

        bf16x8 af0[MF], af1[MF], bf0[4], bf1[4];
#pragma unroll
        for (int m = 0; m < MF; m++) {
            const int base = ((wm * MF + m) * 16 + lq) * 64;
            af0[m] = *(const bf16x8*)&As[buf][base + fsw0];
            af1[m] = *(const bf16x8*)&As[buf][base + fsw1];
        }
#pragma unroll
        for (int n = 0; n < 4; n++) {
            const int base = ((wn * 4 + n) * 16 + lq) * 64;
            bf0[n] = *(const bf16x8*)&Bs[buf][base + fsw0];
            bf1[n] = *(const bf16x8*)&Bs[buf][base + fsw1];
        }
#pragma unroll
        for (int n = 0; n < 4; n++)
#pragma unroll
            for (int m = 0; m < MF; m++) {
                acc[m][n] = __builtin_amdgcn_mfma_f32_16x16x32_bf16(af0[m], bf0[n], acc[m][n], 0, 0, 0);
                acc[m][n] = __builtin_amdgcn_mfma_f32_16x16x32_bf16(af1[m], bf1[n], acc[m][n], 0, 0, 0);
            }
        // separate this iter's LDS reads from next iter's stage overwrite
        __builtin_amdgcn_s_barrier();
    }

    float* Cf = (float*)Cv;
    ushort_t* Cb = (ushort_t*)Cv;
#pragma unroll
    for (int m = 0; m < MF; m++) {
#pragma unroll
        for (int n = 0; n < 4; n++) {
            const int col = tileN + wn * 64 + n * 16 + lq;
            const float bv = bias ? bias[col] : 0.f;
#pragma unroll
            for (int r = 0; r < 4; r++) {
                const int row = tileM + wm * (TM / 2) + m * 16 + quad * 4 + r;
                float v = acc[m][n][r] + bv;
                if (act) v = gelu_f(v);
                const size_t off = (size_t)row * N + col;
                if (resid) v += resid[off];
                if (outbf) Cb[off] = f2bf(v);
                else       Cf[off] = v;
            }
        }
    }
}

// ---------------------------------------------------------------------------
// QK RMSNorm + 2D RoPE, in-place on bf16 at row stride QKVD. One wave per
// (b,n,h) row; lane = dh index. blockIdx.y: 0 -> q (col 0), 1 -> k (col 768).
// ---------------------------------------------------------------------------
__global__ __launch_bounds__(256) void rmsrope_kernel(
    ushort_t* QKV, const float* __restrict__ qg, const float* __restrict__ kg,
    const int* __restrict__ h_idx, const int* __restrict__ w_idx)
{
    const int which = blockIdx.y;
    const float* g = which ? kg : qg;
    ushort_t* X = QKV + which * DIM;

    const int tid  = threadIdx.x;
    const int lane = tid & 63;
    const int r    = blockIdx.x * 4 + (tid >> 6);  // (b*N+n)*H + h
    const int h    = r % NH;
    const int bn   = r / NH;
    const size_t off = (size_t)bn * QKVD + h * DH + lane;

    float v  = bf2f(X[off]);
    float gv = g[h * DH + lane];

    float ss = v * v;
#pragma unroll
    for (int o = 32; o; o >>= 1) ss += __shfl_xor(ss, o);
    float nrm = fmaxf(sqrtf(ss), 1e-12f);
    float val = v / nrm * 8.0f * gv;  // sqrt(DH)=8

    const int idx = (lane < 32) ? h_idx[bn] : w_idx[bn];
    const int f   = lane & 15;
    // 10000^(-f/16) = exp2(-f * log2(10000)/16)
    const float freq = exp2f((float)f * -0.8304820237218407f);
    const float th = (float)idx * freq;
    const float sn = __sinf(th), cs = __cosf(th);
    const float partner = __shfl_xor(val, 16);
    const float outv = ((lane & 31) < 16) ? (val * cs - partner * sn)
                                          : (val * cs + partner * sn);
    X[off] = f2bf(outv);
}

// ---------------------------------------------------------------------------
// V transpose: qkv v-block [B,N,H,DH] -> Vt [B,H,DH,N] bf16. 32x32 LDS tiles.
// ---------------------------------------------------------------------------
__global__ __launch_bounds__(256) void vtrans_kernel(
    const ushort_t* __restrict__ QKV, ushort_t* __restrict__ Vt)
{
    __shared__ ushort_t t[32][33];
    const int bh = blockIdx.x;
    const int b = bh / NH, h = bh % NH;
    const int d0 = blockIdx.y * 32, n0 = blockIdx.z * 32;
    const int tx = threadIdx.x & 31, ty = threadIdx.x >> 5;
#pragma unroll
    for (int r = 0; r < 4; r++) {
        const int n = n0 + ty + r * 8;
        t[ty + r * 8][tx] = QKV[(size_t)(b * NN + n) * QKVD + 2 * DIM + h * DH + d0 + tx];
    }
    __syncthreads();
#pragma unroll
    for (int r = 0; r < 4; r++) {
        const int d = d0 + ty + r * 8;
        Vt[((size_t)(b * NH + h) * DH + d) * NN + n0 + tx] = t[tx][ty + r * 8];
    }
}

// ---------------------------------------------------------------------------
// BF16 MFMA flash attention — r0-EXACT body (measured 92.4-93.1 us).
// Streaming softmax (fixed max = 0; QK-RMSNorm bounds |s| <= 64). Block =
// 4 waves, 64 queries (16/wave). grid (B*H, N/64): wgid%8 == bh%8 -> K/V
// L2-resident per XCD (FETCH 14 MB). Ps stride 76 (152 B): start bank 6*lq
// walks all 16 even banks -> 8.45M conflict cyc (vs 14.79M @ 80).
// r1-r5 micro-variants (queue, setprio, exp2-fold, cvt_pk, tail-split) all
// measured neutral-to-negative; body is locked.
// ---------------------------------------------------------------------------
__global__ __launch_bounds__(256) void attn_kernel(
    const ushort_t* __restrict__ QKV, const ushort_t* __restrict__ Vt_g,
    const int* __restrict__ lengths, ushort_t* __restrict__ O)
{
    __shared__ ushort_t Ks[64 * 64];
    __shared__ ushort_t Vs[64 * 64];
    __shared__ ushort_t Ps[4][16][76];

    const int bh = blockIdx.x;
    const int b  = bh / NH;
    const int h  = bh % NH;
    const int qbase = blockIdx.y * 64;
    const int tid  = threadIdx.x;
    const int w    = tid >> 6;
    const int lane = tid & 63;
    const int lq   = lane & 15;
    const int quad = lane >> 4;
    const int len  = lengths[b];

    const int qrow = qbase + w * 16 + lq;
    const ushort_t* qp = QKV + (size_t)(b * NN + qrow) * QKVD + h * DH + quad * 8;
    bf16x8 aq0 = *(const bf16x8*)(qp);
    bf16x8 aq1 = *(const bf16x8*)(qp + 32);

    const int e0 = tid, e1 = tid + 256;
    const int r0 = e0 >> 3, c80 = e0 & 7;
    const int r1 = e1 >> 3, c81 = e1 & 7;
    const int g0 = (c80 ^ (r0 & 7) ^ (r0 >> 3)) & 7;
    const int g1 = (c81 ^ (r1 & 7) ^ (r1 >> 3)) & 7;
    const ushort_t* kg0 = QKV + (size_t)(b * NN + r0) * QKVD + DIM + h * DH + g0 * 8;
    const ushort_t* kg1 = QKV + (size_t)(b * NN + r1) * QKVD + DIM + h * DH + g1 * 8;
    const ushort_t* vg0 = Vt_g + ((size_t)(b * NH + h) * DH + r0) * NN + g0 * 8;
    const ushort_t* vg1 = Vt_g + ((size_t)(b * NH + h) * DH + r1) * NN + g1 * 8;
    ushort_t* kl0 = Ks + (w * 64) * 8;
    ushort_t* kl1 = Ks + (256 + w * 64) * 8;
    ushort_t* vl0 = Vs + (w * 64) * 8;
    ushort_t* vl1 = Vs + (256 + w * 64) * 8;

    f32x4 oacc[4];
#pragma unroll
    for (int t4 = 0; t4 < 4; t4++) oacc[t4] = (f32x4){0.f, 0.f, 0.f, 0.f};
    float lsum = 0.f;

    const int ntiles = (len + 63) >> 6;
    for (int t = 0; t < ntiles; t++) {
        const int j0 = t * 64;
        gld16(kg0 + (size_t)j0 * QKVD, kl0);
        gld16(kg1 + (size_t)j0 * QKVD, kl1);
        gld16(vg0 + j0, vl0);
        gld16(vg1 + j0, vl1);
        __syncthreads();

        f32x4 s[4];
#pragma unroll
        for (int n = 0; n < 4; n++) {
            const int krow = n * 16 + lq;
            const int hashk = (krow & 7) ^ (krow >> 3);
            bf16x8 ak0 = *(const bf16x8*)&Ks[(krow * 8 + ((quad ^ hashk) & 7)) * 8];
            bf16x8 ak1 = *(const bf16x8*)&Ks[(krow * 8 + (((quad + 4) ^ hashk) & 7)) * 8];
            f32x4 acc = (f32x4){0.f, 0.f, 0.f, 0.f};
            acc = __builtin_amdgcn_mfma_f32_16x16x32_bf16(ak0, aq0, acc, 0, 0, 0);
            acc = __builtin_amdgcn_mfma_f32_16x16x32_bf16(ak1, aq1, acc, 0, 0, 0);
            s[n] = acc;
        }

        float p[4][4];
#pragma unroll
        for (int n = 0; n < 4; n++) {
            const int keyb = j0 + n * 16 + quad * 4;
#pragma unroll
            for (int r = 0; r < 4; r++) {
                float pv = __expf(s[n][r]);
                pv = (keyb + r < len) ? pv : 0.f;
                p[n][r] = pv;
                lsum += pv;
            }
        }

#pragma unroll
        for (int n = 0; n < 4; n++) {
            const unsigned lo = (unsigned)f2bf(p[n][0]) | ((unsigned)f2bf(p[n][1]) << 16);
            const unsigned hi = (unsigned)f2bf(p[n][2]) | ((unsigned)f2bf(p[n][3]) << 16);
            *(uint2*)&Ps[w][lq][n * 16 + quad * 4] = make_uint2(lo, hi);
        }
        asm volatile("s_waitcnt lgkmcnt(0)" ::: "memory");
        bf16x8 ap0 = *(const bf16x8*)&Ps[w][lq][quad * 8];
        bf16x8 ap1 = *(const bf16x8*)&Ps[w][lq][32 + quad * 8];

#pragma unroll
        for (int t4 = 0; t4 < 4; t4++) {
            const int vrow = t4 * 16 + lq;
            const int hashv = (vrow & 7) ^ (vrow >> 3);
            bf16x8 bv0 = *(const bf16x8*)&Vs[(vrow * 8 + ((quad ^ hashv) & 7)) * 8];
            bf16x8 bv1 = *(const bf16x8*)&Vs[(vrow * 8 + (((quad + 4) ^ hashv) & 7)) * 8];
            oacc[t4] = __builtin_amdgcn_mfma_f32_16x16x32_bf16(ap0, bv0, oacc[t4], 0, 0, 0);
            oacc[t4] = __builtin_amdgcn_mfma_f32_16x16x32_bf16(ap1, bv1, oacc[t4], 0, 0, 0);
        }
        __syncthreads();
    }

    lsum += __shfl_xor(lsum, 16);
    lsum += __shfl_xor(lsum, 32);
    float invq[4];
#pragma unroll
    for (int r = 0; r < 4; r++) invq[r] = 1.f / __shfl(lsum, quad * 4 + r);

#pragma unroll
    for (int t4 = 0; t4 < 4; t4++) {
#pragma unroll
        for (int r = 0; r < 4; r++) {
            const int qr = qbase + w * 16 + quad * 4 + r;
            O[((size_t)(b * NN + qr)) * DIM + h * DH + t4 * 16 + lq] = f2bf(oacc[t4][r] * invq[r]);
        }
    }
}

// ---------------------------------------------------------------------------
__global__ __launch_bounds__(256) void mask_kernel(const int* __restrict__ lengths, float* __restrict__ out)
{
    const int i = blockIdx.x * 256 + threadIdx.x;
    const int b = i >> 11;
    const int n = i & (NN - 1);
    out[i] = (n < lengths[b]) ? 1.f : 0.f;
}

// ---------------------------------------------------------------------------
extern "C" void kernel_launch(void* const* d_in, const int* in_sizes, int n_in,
                              void* d_out, int out_size, void* d_ws, size_t ws_size,
                              hipStream_t stream)
{
    const float* patches    = (const float*)d_in[0];
    const float* pe_ln1_g   = (const float*)d_in[1];
    const float* pe_W       = (const float*)d_in[2];
    const float* pe_b       = (const float*)d_in[3];
    const float* pe_ln2_g   = (const float*)d_in[4];
    const float* attn_ln_g  = (const float*)d_in[5];
    const float* qn_g       = (const float*)d_in[6];
    const float* kn_g       = (const float*)d_in[7];
    const float* Wq         = (const float*)d_in[8];
    const float* Wkv        = (const float*)d_in[9];
    const float* Wo         = (const float*)d_in[10];
    const float* ff_ln_g    = (const float*)d_in[11];
    const float* W1         = (const float*)d_in[12];
    const float* b1         = (const float*)d_in[13];
    const float* W2         = (const float*)d_in[14];
    const float* b2         = (const float*)d_in[15];
    const float* final_ln_g = (const float*)d_in[16];
    const int*   h_idx      = (const int*)d_in[17];
    const int*   w_idx      = (const int*)d_in[18];
    const int*   lengths    = (const int*)d_in[19];

    float* out = (float*)d_out;
    char*  p   = (char*)d_ws;

    const size_t MB = 1024 * 1024;
    ushort_t* wbf = (ushort_t*)p;                       // ~28.1 MiB of bf16 weights
    ushort_t* peWt = wbf;
    size_t woff = (size_t)DIM * DIM;                    // 589824
    ushort_t* Wqkvt[LNUM], *Wot[LNUM], *W1t[LNUM], *W2t[LNUM];
    for (int i = 0; i < LNUM; i++) {
        Wqkvt[i] = wbf + woff; woff += (size_t)QKVD * DIM;  // q rows then kv rows
        Wot[i]   = wbf + woff; woff += (size_t)DIM * DIM;
        W1t[i]   = wbf + woff; woff += (size_t)DIM * MLPD;
        W2t[i]   = wbf + woff; woff += (size_t)MLPD * DIM;
    }
    ushort_t* xnbf = (ushort_t*)(p + 30 * MB);          // [8192,768]  12.6 MB
    ushort_t* qkv  = (ushort_t*)(p + 43 * MB);          // [8192,2304] 37.7 MB
    ushort_t* aob  = (ushort_t*)(p + 82 * MB);          // [8192,768]  12.6 MB
    ushort_t* hb   = (ushort_t*)(p + 43 * MB);          // [8192,3072] 50.3 MB (qkv dead)
    float*    peF  = (float*)(p + 43 * MB);             // [8192,768] fp32 (pe only)
    ushort_t* vtg  = (ushort_t*)(p + 96 * MB);          // [B,H,DH,N]  12.6 MB

    const int ROWS = BB * NN;  // 8192
    dim3 blk(256);
    dim3 blkln(192);

    // ---- ALL weight converts in one launch (14400 tiles) ----
    wconvert_all_kernel<<<dim3(576 + LNUM * 6912), blk, 0, stream>>>(
        pe_W, Wq, Wkv, Wo, W1, W2, wbf);

    // ---- patch embedding: LN -> GEMM(+bias) -> LN ----
    ln_kernel<ushort_t><<<ROWS, blkln, 0, stream>>>(patches, pe_ln1_g, xnbf);
    gemm_bf<64><<<dim3(DIM / 128, ROWS / 64), blk, 0, stream>>>(
        xnbf, peWt, pe_b, nullptr, peF, ROWS, DIM, DIM, 0, 0);
    ln_kernel<float><<<ROWS, blkln, 0, stream>>>(peF, pe_ln2_g, out);

    float* x = out;  // residual stream lives in d_out
    for (int i = 0; i < LNUM; i++) {
        ln_kernel<ushort_t><<<ROWS, blkln, 0, stream>>>(x, attn_ln_g + i * DIM, xnbf);
        gemm_bf<128><<<dim3(QKVD / 128, ROWS / 128), blk, 0, stream>>>(
            xnbf, Wqkvt[i], nullptr, nullptr, qkv, ROWS, QKVD, DIM, 1, 0);
        rmsrope_kernel<<<dim3(ROWS * NH / 4, 2), blk, 0, stream>>>(
            qkv, qn_g + i * NH * DH, kn_g + i * NH * DH, h_idx, w_idx);
        vtrans_kernel<<<dim3(BB * NH, DH / 32, NN / 32), blk, 0, stream>>>(qkv, vtg);
        attn_kernel<<<dim3(BB * NH, NN / 64), blk, 0, stream>>>(
            qkv, vtg, lengths, aob);
        gemm_bf<64><<<dim3(DIM / 128, ROWS / 64), blk, 0, stream>>>(
            aob, Wot[i], nullptr, x, x, ROWS, DIM, DIM, 0, 0);
        ln_kernel<ushort_t><<<ROWS, blkln, 0, stream>>>(x, ff_ln_g + i * DIM, xnbf);
        gemm_bf<128><<<dim3(MLPD / 128, ROWS / 128), blk, 0, stream>>>(
            xnbf, W1t[i], b1 + i * MLPD, nullptr, hb, ROWS, MLPD, DIM, 1, 1);
        // r9: W2 TM=64 -> TM=128 (grid 6x64=384 @ 2/CU = 75% fill; staging
        // intensity 131 vs 44 FLOP/B; K=3072 amortizes prologue best)
        gemm_bf<128><<<dim3(DIM / 128, ROWS / 128), blk, 0, stream>>>(
            hb, W2t[i], b2 + i * DIM, x, x, ROWS, DIM, MLPD, 0, 0);
    }
    ln_kernel<float><<<ROWS, blkln, 0, stream>>>(x, final_ln_g, out);
    mask_kernel<<<ROWS / 256, blk, 0, stream>>>(lengths, out + (size_t)ROWS * DIM);
}

// Round 10
// 908.577 us; speedup vs baseline: 1.0230x; 1.0230x over previous
//
#include <hip/hip_runtime.h>
#include <math.h>

// Problem constants (NaViT encoder)
#define LNUM 2
#define BB   4
#define NN   2048
#define DIM  768
#define NH   12
#define DH   64
#define MLPD 3072
#define QKVD 2304   // fused q|k|v row stride

typedef __attribute__((ext_vector_type(8))) short bf16x8;
typedef __attribute__((ext_vector_type(4))) float f32x4;
typedef unsigned short ushort_t;

__device__ __forceinline__ ushort_t f2bf(float f) {
    union { float f; unsigned u; } v; v.f = f;
    unsigned r = v.u + 0x7fff + ((v.u >> 16) & 1);  // RNE
    return (ushort_t)(r >> 16);
}
__device__ __forceinline__ float bf2f(ushort_t s) {
    union { unsigned u; float f; } v; v.u = ((unsigned)s) << 16;
    return v.f;
}
__device__ __forceinline__ void gld16(const void* g, void* l) {
    __builtin_amdgcn_global_load_lds(
        (const __attribute__((address_space(1))) void*)g,
        (__attribute__((address_space(3))) void*)l, 16, 0, 0);
}
// tanh-form GELU (max |err| vs exact erf-GELU ~3e-4 — invisible at bf16)
__device__ __forceinline__ float gelu_f(float x) {
    const float y = 0.7978845608028654f * (x + 0.044715f * x * x * x);
    const float t = 1.f - 2.f / (1.f + __expf(2.f * y));  // tanh(y), inf-safe
    return 0.5f * x * (1.f + t);
}

// ---------------------------------------------------------------------------
// Fused weight convert+transpose for ALL weights in ONE launch (was 11
// dispatches). Each block does one 32x32 tile; compile-time range table maps
// blockIdx -> (src, dst, K, N). W fp32 [K,N] -> Wt bf16 [N,K].
// ---------------------------------------------------------------------------
#define WOFF_L 7077888
__global__ __launch_bounds__(256) void wconvert_all_kernel(
    const float* __restrict__ peW, const float* __restrict__ Wq,
    const float* __restrict__ Wkv, const float* __restrict__ Wo,
    const float* __restrict__ W1, const float* __restrict__ W2,
    ushort_t* __restrict__ wbf)
{
    int bid = blockIdx.x;
    const float* src; ushort_t* dst; int K, N;
    // per-layer tile counts: Wq 576, Wkv 1152, Wo 576, W1 2304, W2 2304 = 6912
    if (bid < 576)        { src = peW;                      dst = wbf;                               K = 768;  N = 768;  }
    else {
        bid -= 576;
        const int layer = bid / 6912;
        int t = bid % 6912;
        const size_t lw = (size_t)layer * WOFF_L;
        if (t < 576)        {           src = Wq  + (size_t)layer * 768 * 768;   dst = wbf + 589824 + lw;           K = 768;  N = 768;  }
        else if (t < 1728)  { t -= 576; src = Wkv + (size_t)layer * 768 * 1536;  dst = wbf + 589824 + 589824 + lw;  K = 768;  N = 1536; }
        else if (t < 2304)  { t -= 1728; src = Wo + (size_t)layer * 768 * 768;   dst = wbf + 589824 + 1769472 + lw; K = 768;  N = 768;  }
        else if (t < 4608)  { t -= 2304; src = W1 + (size_t)layer * 768 * 3072;  dst = wbf + 589824 + 2359296 + lw; K = 768;  N = 3072; }
        else                { t -= 4608; src = W2 + (size_t)layer * 3072 * 768;  dst = wbf + 589824 + 4718592 + lw; K = 3072; N = 768;  }
        bid = t;
    }
    const int tilesN = N / 32;
    const int nt = (bid % tilesN) * 32, kt = (bid / tilesN) * 32;

    __shared__ ushort_t tl[32][33];
    const int tx = threadIdx.x & 31, ty = threadIdx.x >> 5;  // ty 0..7
#pragma unroll
    for (int r = 0; r < 4; r++) {
        const int k = kt + ty + r * 8;
        tl[ty + r * 8][tx] = f2bf(src[(size_t)k * N + nt + tx]);
    }
    __syncthreads();
#pragma unroll
    for (int r = 0; r < 4; r++) {
        const int n = nt + ty + r * 8;
        dst[(size_t)n * K + kt + tx] = tl[tx][ty + r * 8];
    }
}

// ---------------------------------------------------------------------------
// LayerNorm over last dim (768). One block (192 thr = 3 waves) per row;
// each thread owns 4 consecutive floats: ONE dwordx4 load + ONE 8B packed
// store (r9, G13 — was 3 scalar loads + 3 scalar stores). OT: float|ushort
// ---------------------------------------------------------------------------
template <typename OT>
__global__ __launch_bounds__(192) void ln_kernel(const float* in, const float* g, OT* out)
{
    const int row = blockIdx.x;
    const int tid = threadIdx.x;
    const float4 v = *(const float4*)(in + (size_t)row * DIM + tid * 4);
    float s  = (v.x + v.y) + (v.z + v.w);
    float s2 = (v.x * v.x + v.y * v.y) + (v.z * v.z + v.w * v.w);
#pragma unroll
    for (int o = 32; o; o >>= 1) {
        s  += __shfl_xor(s, o);
        s2 += __shfl_xor(s2, o);
    }
    __shared__ float red[6];
    const int wid = tid >> 6;  // 0..2
    if ((tid & 63) == 0) { red[wid] = s; red[wid + 3] = s2; }
    __syncthreads();
    s  = red[0] + red[1] + red[2];
    s2 = red[3] + red[4] + red[5];
    const float mean = s * (1.f / DIM);
    const float var  = s2 * (1.f / DIM) - mean * mean;
    const float inv  = rsqrtf(var + 1e-5f);
    const float4 gv = *(const float4*)(g + tid * 4);
    const float o0 = (v.x - mean) * inv * gv.x;
    const float o1 = (v.y - mean) * inv * gv.y;
    const float o2 = (v.z - mean) * inv * gv.z;
    const float o3 = (v.w - mean) * inv * gv.w;
    if constexpr (sizeof(OT) == 2) {
        const unsigned lo = (unsigned)f2bf(o0) | ((unsigned)f2bf(o1) << 16);
        const unsigned hi = (unsigned)f2bf(o2) | ((unsigned)f2bf(o3) << 16);
        *(uint2*)((ushort_t*)out + (size_t)row * DIM + tid * 4) = make_uint2(lo, hi);
    } else {
        *(float4*)((float*)out + (size_t)row * DIM + tid * 4) = make_float4(o0, o1, o2, o3);
    }
}

// ---------------------------------------------------------------------------
// BF16 MFMA GEMM: C[M,N] = act(A[M,K] @ Bt[N,K]^T + bias) + resid
// TM x 128 tile, BK=64, 256 thr = 4 waves (2x2), 16x16x32 MFMA.
// Staging swizzle: 8 lanes/row (128B), chunk ^= row&7 -> conflict-free
// fragment reads (SQ_LDS_BANK_CONFLICT = 0 measured).
//
// Structure: dbuf + counted s_waitcnt vmcnt(NL) + raw s_barrier (T3+T4, r8:
// total -16 us on TM=64 GEMMs; W1 schedule-invariant at ~100 us).
//
// TM RULE (r4 + r9, twice-measured): grid EVENNESS dominates staging
// intensity. N=768 outputs MUST be TM=64 (768 blocks = 3/CU exactly even);
// TM=128 gives 384 blocks -> half the CUs run 2 sequential blocks, half
// run 1 -> ~33% makespan loss (r4: -74 us over 3 GEMMs; r9: -32 us on W2
// alone, despite 131 vs 44 FLOP/B intensity). TM=128 only where the grid
// stays >= 4 blocks/CU-ish: QKV (1152 blk = 4.5/CU), W1 (1536 = 6/CU).
// ---------------------------------------------------------------------------
template <int TM>
__global__ __launch_bounds__(256) void gemm_bf(
    const ushort_t* __restrict__ A, const ushort_t* __restrict__ Bt,
    const float* __restrict__ bias, const float* __restrict__ resid,
    void* __restrict__ Cv, int M, int N, int K, int outbf, int act)
{
    constexpr int MF = TM / 32;  // m-frags per wave: 4 (TM=128) or 2 (TM=64)
    constexpr int AG = TM / 32;  // A staging groups of 32 rows
    __shared__ ushort_t As[2][TM * 64];
    __shared__ ushort_t Bs[2][128 * 64];
    const int tid  = threadIdx.x;
    const int w    = tid >> 6, lane = tid & 63;
    const int lq   = lane & 15, quad = lane >> 4;
    const int wm   = w & 1, wn = w >> 1;
    const int tileM = blockIdx.y * TM, tileN = blockIdx.x * 128;

    // staging coords: row-within-group = w*8 + (lane>>3); chunk = (lane&7)^srow
    const int srow   = lane >> 3;                 // 0..7
    const int schunk = (lane & 7) ^ srow;         // swizzled k-chunk (8 ushorts)
    const ushort_t* agp[AG];
    const ushort_t* bgp[4];
#pragma unroll
    for (int g = 0; g < AG; g++)
        agp[g] = A + (size_t)(tileM + g * 32 + w * 8 + srow) * K + schunk * 8;
#pragma unroll
    for (int g = 0; g < 4; g++)
        bgp[g] = Bt + (size_t)(tileN + g * 32 + w * 8 + srow) * K + schunk * 8;

    f32x4 acc[MF][4];
#pragma unroll
    for (int m = 0; m < MF; m++)
#pragma unroll
        for (int n = 0; n < 4; n++) acc[m][n] = (f32x4){0.f, 0.f, 0.f, 0.f};

    const int fsw0 = (quad ^ (lq & 7)) * 8;       // chunk quad   slot offset
    const int fsw1 = ((quad ^ (lq & 7)) ^ 4) * 8; // chunk quad+4 slot offset

    // prologue: stage tile 0 into buf 0 (NL loads in flight)
#pragma unroll
    for (int g = 0; g < AG; g++)
        gld16(agp[g], As[0] + (g * 32 + w * 8) * 64);
#pragma unroll
    for (int g = 0; g < 4; g++)
        gld16(bgp[g], Bs[0] + (g * 32 + w * 8) * 64);

    int buf = 0;
    for (int kt = 0; kt < K; kt += 64, buf ^= 1) {
        if (kt + 64 < K) {
            // stage NEXT tile into the other buffer (issue-only)
#pragma unroll
            for (int g = 0; g < AG; g++)
                gld16(agp[g] + kt + 64, As[buf ^ 1] + (g * 32 + w * 8) * 64);
#pragma unroll
            for (int g = 0; g < 4; g++)
                gld16(bgp[g] + kt + 64, Bs[buf ^ 1] + (g * 32 + w * 8) * 64);
            // wait for TILE t's loads only; tile t+1's NL loads stay in flight
            if constexpr (TM == 128) asm volatile("s_waitcnt vmcnt(8)" ::: "memory");
            else                     asm volatile("s_waitcnt vmcnt(6)" ::: "memory");
        } else {
            asm volatile("s_waitcnt vmcnt(0)" ::: "memory");
        }
        __builtin_amdgcn_s_barrier();   // raw: no compiler vmcnt(0) drain

        bf16x8 af0[MF], af1[MF], bf0[4], bf1[4];
#pragma unroll
        for (int m = 0; m < MF; m++) {
            const int base = ((wm * MF + m) * 16 + lq) * 64;
            af0[m] = *(const bf16x8*)&As[buf][base + fsw0];
            af1[m] = *(const bf16x8*)&As[buf][base + fsw1];
        }
#pragma unroll
        for (int n = 0; n < 4; n++) {
            const int base = ((wn * 4 + n) * 16 + lq) * 64;
            bf0[n] = *(const bf16x8*)&Bs[buf][base + fsw0];
            bf1[n] = *(const bf16x8*)&Bs[buf][base + fsw1];
        }
#pragma unroll
        for (int n = 0; n < 4; n++)
#pragma unroll
            for (int m = 0; m < MF; m++) {
                acc[m][n] = __builtin_amdgcn_mfma_f32_16x16x32_bf16(af0[m], bf0[n], acc[m][n], 0, 0, 0);
                acc[m][n] = __builtin_amdgcn_mfma_f32_16x16x32_bf16(af1[m], bf1[n], acc[m][n], 0, 0, 0);
            }
        // separate this iter's LDS reads from next iter's stage overwrite
        __builtin_amdgcn_s_barrier();
    }

    float* Cf = (float*)Cv;
    ushort_t* Cb = (ushort_t*)Cv;
#pragma unroll
    for (int m = 0; m < MF; m++) {
#pragma unroll
        for (int n = 0; n < 4; n++) {
            const int col = tileN + wn * 64 + n * 16 + lq;
            const float bv = bias ? bias[col] : 0.f;
#pragma unroll
            for (int r = 0; r < 4; r++) {
                const int row = tileM + wm * (TM / 2) + m * 16 + quad * 4 + r;
                float v = acc[m][n][r] + bv;
                if (act) v = gelu_f(v);
                const size_t off = (size_t)row * N + col;
                if (resid) v += resid[off];
                if (outbf) Cb[off] = f2bf(v);
                else       Cf[off] = v;
            }
        }
    }
}

// ---------------------------------------------------------------------------
// QK RMSNorm + 2D RoPE, in-place on bf16 at row stride QKVD. One wave per
// (b,n,h) row; lane = dh index. blockIdx.y: 0 -> q (col 0), 1 -> k (col 768).
// ---------------------------------------------------------------------------
__global__ __launch_bounds__(256) void rmsrope_kernel(
    ushort_t* QKV, const float* __restrict__ qg, const float* __restrict__ kg,
    const int* __restrict__ h_idx, const int* __restrict__ w_idx)
{
    const int which = blockIdx.y;
    const float* g = which ? kg : qg;
    ushort_t* X = QKV + which * DIM;

    const int tid  = threadIdx.x;
    const int lane = tid & 63;
    const int r    = blockIdx.x * 4 + (tid >> 6);  // (b*N+n)*H + h
    const int h    = r % NH;
    const int bn   = r / NH;
    const size_t off = (size_t)bn * QKVD + h * DH + lane;

    float v  = bf2f(X[off]);
    float gv = g[h * DH + lane];

    float ss = v * v;
#pragma unroll
    for (int o = 32; o; o >>= 1) ss += __shfl_xor(ss, o);
    float nrm = fmaxf(sqrtf(ss), 1e-12f);
    float val = v / nrm * 8.0f * gv;  // sqrt(DH)=8

    const int idx = (lane < 32) ? h_idx[bn] : w_idx[bn];
    const int f   = lane & 15;
    // 10000^(-f/16) = exp2(-f * log2(10000)/16)
    const float freq = exp2f((float)f * -0.8304820237218407f);
    const float th = (float)idx * freq;
    const float sn = __sinf(th), cs = __cosf(th);
    const float partner = __shfl_xor(val, 16);
    const float outv = ((lane & 31) < 16) ? (val * cs - partner * sn)
                                          : (val * cs + partner * sn);
    X[off] = f2bf(outv);
}

// ---------------------------------------------------------------------------
// V transpose: qkv v-block [B,N,H,DH] -> Vt [B,H,DH,N] bf16. 32x32 LDS tiles.
// ---------------------------------------------------------------------------
__global__ __launch_bounds__(256) void vtrans_kernel(
    const ushort_t* __restrict__ QKV, ushort_t* __restrict__ Vt)
{
    __shared__ ushort_t t[32][33];
    const int bh = blockIdx.x;
    const int b = bh / NH, h = bh % NH;
    const int d0 = blockIdx.y * 32, n0 = blockIdx.z * 32;
    const int tx = threadIdx.x & 31, ty = threadIdx.x >> 5;
#pragma unroll
    for (int r = 0; r < 4; r++) {
        const int n = n0 + ty + r * 8;
        t[ty + r * 8][tx] = QKV[(size_t)(b * NN + n) * QKVD + 2 * DIM + h * DH + d0 + tx];
    }
    __syncthreads();
#pragma unroll
    for (int r = 0; r < 4; r++) {
        const int d = d0 + ty + r * 8;
        Vt[((size_t)(b * NH + h) * DH + d) * NN + n0 + tx] = t[tx][ty + r * 8];
    }
}

// ---------------------------------------------------------------------------
// BF16 MFMA flash attention — r0-EXACT body (measured 91.2-93.1 us).
// Streaming softmax (fixed max = 0; QK-RMSNorm bounds |s| <= 64). Block =
// 4 waves, 64 queries (16/wave). grid (B*H, N/64): wgid%8 == bh%8 -> K/V
// L2-resident per XCD (FETCH 14 MB). Ps stride 76 (152 B): start bank 6*lq
// walks all 16 even banks -> 8.45M conflict cyc (vs 14.79M @ 80).
// r1-r5 micro-variants (queue, setprio, exp2-fold, cvt_pk, tail-split) all
// measured neutral-to-negative; body is locked.
// ---------------------------------------------------------------------------
__global__ __launch_bounds__(256) void attn_kernel(
    const ushort_t* __restrict__ QKV, const ushort_t* __restrict__ Vt_g,
    const int* __restrict__ lengths, ushort_t* __restrict__ O)
{
    __shared__ ushort_t Ks[64 * 64];
    __shared__ ushort_t Vs[64 * 64];
    __shared__ ushort_t Ps[4][16][76];

    const int bh = blockIdx.x;
    const int b  = bh / NH;
    const int h  = bh % NH;
    const int qbase = blockIdx.y * 64;
    const int tid  = threadIdx.x;
    const int w    = tid >> 6;
    const int lane = tid & 63;
    const int lq   = lane & 15;
    const int quad = lane >> 4;
    const int len  = lengths[b];

    const int qrow = qbase + w * 16 + lq;
    const ushort_t* qp = QKV + (size_t)(b * NN + qrow) * QKVD + h * DH + quad * 8;
    bf16x8 aq0 = *(const bf16x8*)(qp);
    bf16x8 aq1 = *(const bf16x8*)(qp + 32);

    const int e0 = tid, e1 = tid + 256;
    const int r0 = e0 >> 3, c80 = e0 & 7;
    const int r1 = e1 >> 3, c81 = e1 & 7;
    const int g0 = (c80 ^ (r0 & 7) ^ (r0 >> 3)) & 7;
    const int g1 = (c81 ^ (r1 & 7) ^ (r1 >> 3)) & 7;
    const ushort_t* kg0 = QKV + (size_t)(b * NN + r0) * QKVD + DIM + h * DH + g0 * 8;
    const ushort_t* kg1 = QKV + (size_t)(b * NN + r1) * QKVD + DIM + h * DH + g1 * 8;
    const ushort_t* vg0 = Vt_g + ((size_t)(b * NH + h) * DH + r0) * NN + g0 * 8;
    const ushort_t* vg1 = Vt_g + ((size_t)(b * NH + h) * DH + r1) * NN + g1 * 8;
    ushort_t* kl0 = Ks + (w * 64) * 8;
    ushort_t* kl1 = Ks + (256 + w * 64) * 8;
    ushort_t* vl0 = Vs + (w * 64) * 8;
    ushort_t* vl1 = Vs + (256 + w * 64) * 8;

    f32x4 oacc[4];
#pragma unroll
    for (int t4 = 0; t4 < 4; t4++) oacc[t4] = (f32x4){0.f, 0.f, 0.f, 0.f};
    float lsum = 0.f;

    const int ntiles = (len + 63) >> 6;
    for (int t = 0; t < ntiles; t++) {
        const int j0 = t * 64;
        gld16(kg0 + (size_t)j0 * QKVD, kl0);
        gld16(kg1 + (size_t)j0 * QKVD, kl1);
        gld16(vg0 + j0, vl0);
        gld16(vg1 + j0, vl1);
        __syncthreads();

        f32x4 s[4];
#pragma unroll
        for (int n = 0; n < 4; n++) {
            const int krow = n * 16 + lq;
            const int hashk = (krow & 7) ^ (krow >> 3);
            bf16x8 ak0 = *(const bf16x8*)&Ks[(krow * 8 + ((quad ^ hashk) & 7)) * 8];
            bf16x8 ak1 = *(const bf16x8*)&Ks[(krow * 8 + (((quad + 4) ^ hashk) & 7)) * 8];
            f32x4 acc = (f32x4){0.f, 0.f, 0.f, 0.f};
            acc = __builtin_amdgcn_mfma_f32_16x16x32_bf16(ak0, aq0, acc, 0, 0, 0);
            acc = __builtin_amdgcn_mfma_f32_16x16x32_bf16(ak1, aq1, acc, 0, 0, 0);
            s[n] = acc;
        }

        float p[4][4];
#pragma unroll
        for (int n = 0; n < 4; n++) {
            const int keyb = j0 + n * 16 + quad * 4;
#pragma unroll
            for (int r = 0; r < 4; r++) {
                float pv = __expf(s[n][r]);
                pv = (keyb + r < len) ? pv : 0.f;
                p[n][r] = pv;
                lsum += pv;
            }
        }

#pragma unroll
        for (int n = 0; n < 4; n++) {
            const unsigned lo = (unsigned)f2bf(p[n][0]) | ((unsigned)f2bf(p[n][1]) << 16);
            const unsigned hi = (unsigned)f2bf(p[n][2]) | ((unsigned)f2bf(p[n][3]) << 16);
            *(uint2*)&Ps[w][lq][n * 16 + quad * 4] = make_uint2(lo, hi);
        }
        asm volatile("s_waitcnt lgkmcnt(0)" ::: "memory");
        bf16x8 ap0 = *(const bf16x8*)&Ps[w][lq][quad * 8];
        bf16x8 ap1 = *(const bf16x8*)&Ps[w][lq][32 + quad * 8];

#pragma unroll
        for (int t4 = 0; t4 < 4; t4++) {
            const int vrow = t4 * 16 + lq;
            const int hashv = (vrow & 7) ^ (vrow >> 3);
            bf16x8 bv0 = *(const bf16x8*)&Vs[(vrow * 8 + ((quad ^ hashv) & 7)) * 8];
            bf16x8 bv1 = *(const bf16x8*)&Vs[(vrow * 8 + (((quad + 4) ^ hashv) & 7)) * 8];
            oacc[t4] = __builtin_amdgcn_mfma_f32_16x16x32_bf16(ap0, bv0, oacc[t4], 0, 0, 0);
            oacc[t4] = __builtin_amdgcn_mfma_f32_16x16x32_bf16(ap1, bv1, oacc[t4], 0, 0, 0);
        }
        __syncthreads();
    }

    lsum += __shfl_xor(lsum, 16);
    lsum += __shfl_xor(lsum, 32);
    float invq[4];
#pragma unroll
    for (int r = 0; r < 4; r++) invq[r] = 1.f / __shfl(lsum, quad * 4 + r);

#pragma unroll
    for (int t4 = 0; t4 < 4; t4++) {
#pragma unroll
        for (int r = 0; r < 4; r++) {
            const int qr = qbase + w * 16 + quad * 4 + r;
            O[((size_t)(b * NN + qr)) * DIM + h * DH + t4 * 16 + lq] = f2bf(oacc[t4][r] * invq[r]);
        }
    }
}

// ---------------------------------------------------------------------------
__global__ __launch_bounds__(256) void mask_kernel(const int* __restrict__ lengths, float* __restrict__ out)
{
    const int i = blockIdx.x * 256 + threadIdx.x;
    const int b = i >> 11;
    const int n = i & (NN - 1);
    out[i] = (n < lengths[b]) ? 1.f : 0.f;
}

// ---------------------------------------------------------------------------
extern "C" void kernel_launch(void* const* d_in, const int* in_sizes, int n_in,
                              void* d_out, int out_size, void* d_ws, size_t ws_size,
                              hipStream_t stream)
{
    const float* patches    = (const float*)d_in[0];
    const float* pe_ln1_g   = (const float*)d_in[1];
    const float* pe_W       = (const float*)d_in[2];
    const float* pe_b       = (const float*)d_in[3];
    const float* pe_ln2_g   = (const float*)d_in[4];
    const float* attn_ln_g  = (const float*)d_in[5];
    const float* qn_g       = (const float*)d_in[6];
    const float* kn_g       = (const float*)d_in[7];
    const float* Wq         = (const float*)d_in[8];
    const float* Wkv        = (const float*)d_in[9];
    const float* Wo         = (const float*)d_in[10];
    const float* ff_ln_g    = (const float*)d_in[11];
    const float* W1         = (const float*)d_in[12];
    const float* b1         = (const float*)d_in[13];
    const float* W2         = (const float*)d_in[14];
    const float* b2         = (const float*)d_in[15];
    const float* final_ln_g = (const float*)d_in[16];
    const int*   h_idx      = (const int*)d_in[17];
    const int*   w_idx      = (const int*)d_in[18];
    const int*   lengths    = (const int*)d_in[19];

    float* out = (float*)d_out;
    char*  p   = (char*)d_ws;

    const size_t MB = 1024 * 1024;
    ushort_t* wbf = (ushort_t*)p;                       // ~28.1 MiB of bf16 weights
    ushort_t* peWt = wbf;
    size_t woff = (size_t)DIM * DIM;                    // 589824
    ushort_t* Wqkvt[LNUM], *Wot[LNUM], *W1t[LNUM], *W2t[LNUM];
    for (int i = 0; i < LNUM; i++) {
        Wqkvt[i] = wbf + woff; woff += (size_t)QKVD * DIM;  // q rows then kv rows
        Wot[i]   = wbf + woff; woff += (size_t)DIM * DIM;
        W1t[i]   = wbf + woff; woff += (size_t)DIM * MLPD;
        W2t[i]   = wbf + woff; woff += (size_t)MLPD * DIM;
    }
    ushort_t* xnbf = (ushort_t*)(p + 30 * MB);          // [8192,768]  12.6 MB
    ushort_t* qkv  = (ushort_t*)(p + 43 * MB);          // [8192,2304] 37.7 MB
    ushort_t* aob  = (ushort_t*)(p + 82 * MB);          // [8192,768]  12.6 MB
    ushort_t* hb   = (ushort_t*)(p + 43 * MB);          // [8192,3072] 50.3 MB (qkv dead)
    float*    peF  = (float*)(p + 43 * MB);             // [8192,768] fp32 (pe only)
    ushort_t* vtg  = (ushort_t*)(p + 96 * MB);          // [B,H,DH,N]  12.6 MB

    const int ROWS = BB * NN;  // 8192
    dim3 blk(256);
    dim3 blkln(192);

    // ---- ALL weight converts in one launch (14400 tiles) ----
    wconvert_all_kernel<<<dim3(576 + LNUM * 6912), blk, 0, stream>>>(
        pe_W, Wq, Wkv, Wo, W1, W2, wbf);

    // ---- patch embedding: LN -> GEMM(+bias) -> LN ----
    ln_kernel<ushort_t><<<ROWS, blkln, 0, stream>>>(patches, pe_ln1_g, xnbf);
    gemm_bf<64><<<dim3(DIM / 128, ROWS / 64), blk, 0, stream>>>(
        xnbf, peWt, pe_b, nullptr, peF, ROWS, DIM, DIM, 0, 0);
    ln_kernel<float><<<ROWS, blkln, 0, stream>>>(peF, pe_ln2_g, out);

    float* x = out;  // residual stream lives in d_out
    for (int i = 0; i < LNUM; i++) {
        ln_kernel<ushort_t><<<ROWS, blkln, 0, stream>>>(x, attn_ln_g + i * DIM, xnbf);
        gemm_bf<128><<<dim3(QKVD / 128, ROWS / 128), blk, 0, stream>>>(
            xnbf, Wqkvt[i], nullptr, nullptr, qkv, ROWS, QKVD, DIM, 1, 0);
        rmsrope_kernel<<<dim3(ROWS * NH / 4, 2), blk, 0, stream>>>(
            qkv, qn_g + i * NH * DH, kn_g + i * NH * DH, h_idx, w_idx);
        vtrans_kernel<<<dim3(BB * NH, DH / 32, NN / 32), blk, 0, stream>>>(qkv, vtg);
        attn_kernel<<<dim3(BB * NH, NN / 64), blk, 0, stream>>>(
            qkv, vtg, lengths, aob);
        gemm_bf<64><<<dim3(DIM / 128, ROWS / 64), blk, 0, stream>>>(
            aob, Wot[i], nullptr, x, x, ROWS, DIM, DIM, 0, 0);
        ln_kernel<ushort_t><<<ROWS, blkln, 0, stream>>>(x, ff_ln_g + i * DIM, xnbf);
        gemm_bf<128><<<dim3(MLPD / 128, ROWS / 128), blk, 0, stream>>>(
            xnbf, W1t[i], b1 + i * MLPD, nullptr, hb, ROWS, MLPD, DIM, 1, 1);
        // r10: W2 back to TM=64 (r9's TM=128 = -32 us: 384 blocks -> uneven
        // 2-vs-1 blocks/CU makespan; TM rule in gemm_bf header)
        gemm_bf<64><<<dim3(DIM / 128, ROWS / 64), blk, 0, stream>>>(
            hb, W2t[i], b2 + i * DIM, x, x, ROWS, DIM, MLPD, 0, 0);
    }
    ln_kernel<float><<<ROWS, blkln, 0, stream>>>(x, final_ln_g, out);
    mask_kernel<<<ROWS / 256, blk, 0, stream>>>(lengths, out + (size_t)ROWS * DIM);
}

// Round 11
// 836.724 us; speedup vs baseline: 1.1108x; 1.0859x over previous
//
#include <hip/hip_runtime.h>
#include <math.h>

// Problem constants (NaViT encoder)
#define LNUM 2
#define BB   4
#define NN   2048
#define DIM  768
#define NH   12
#define DH   64
#define MLPD 3072
#define QKVD 2304   // fused q|k|v row stride

typedef __attribute__((ext_vector_type(8))) short bf16x8;
typedef __attribute__((ext_vector_type(4))) float f32x4;
typedef unsigned short ushort_t;

__device__ __forceinline__ ushort_t f2bf(float f) {
    union { float f; unsigned u; } v; v.f = f;
    unsigned r = v.u + 0x7fff + ((v.u >> 16) & 1);  // RNE
    return (ushort_t)(r >> 16);
}
__device__ __forceinline__ float bf2f(ushort_t s) {
    union { unsigned u; float f; } v; v.u = ((unsigned)s) << 16;
    return v.f;
}
__device__ __forceinline__ void gld16(const void* g, void* l) {
    __builtin_amdgcn_global_load_lds(
        (const __attribute__((address_space(1))) void*)g,
        (__attribute__((address_space(3))) void*)l, 16, 0, 0);
}
// tanh-form GELU (max |err| vs exact erf-GELU ~3e-4 — invisible at bf16)
__device__ __forceinline__ float gelu_f(float x) {
    const float y = 0.7978845608028654f * (x + 0.044715f * x * x * x);
    const float t = 1.f - 2.f / (1.f + __expf(2.f * y));  // tanh(y), inf-safe
    return 0.5f * x * (1.f + t);
}

// ---------------------------------------------------------------------------
// Fused weight convert+transpose for ALL weights in ONE launch (was 11
// dispatches). Each block does one 32x32 tile; compile-time range table maps
// blockIdx -> (src, dst, K, N). W fp32 [K,N] -> Wt bf16 [N,K].
// ---------------------------------------------------------------------------
#define WOFF_L 7077888
__global__ __launch_bounds__(256) void wconvert_all_kernel(
    const float* __restrict__ peW, const float* __restrict__ Wq,
    const float* __restrict__ Wkv, const float* __restrict__ Wo,
    const float* __restrict__ W1, const float* __restrict__ W2,
    ushort_t* __restrict__ wbf)
{
    int bid = blockIdx.x;
    const float* src; ushort_t* dst; int K, N;
    // per-layer tile counts: Wq 576, Wkv 1152, Wo 576, W1 2304, W2 2304 = 6912
    if (bid < 576)        { src = peW;                      dst = wbf;                               K = 768;  N = 768;  }
    else {
        bid -= 576;
        const int layer = bid / 6912;
        int t = bid % 6912;
        const size_t lw = (size_t)layer * WOFF_L;
        if (t < 576)        {           src = Wq  + (size_t)layer * 768 * 768;   dst = wbf + 589824 + lw;           K = 768;  N = 768;  }
        else if (t < 1728)  { t -= 576; src = Wkv + (size_t)layer * 768 * 1536;  dst = wbf + 589824 + 589824 + lw;  K = 768;  N = 1536; }
        else if (t < 2304)  { t -= 1728; src = Wo + (size_t)layer * 768 * 768;   dst = wbf + 589824 + 1769472 + lw; K = 768;  N = 768;  }
        else if (t < 4608)  { t -= 2304; src = W1 + (size_t)layer * 768 * 3072;  dst = wbf + 589824 + 2359296 + lw; K = 768;  N = 3072; }
        else                { t -= 4608; src = W2 + (size_t)layer * 3072 * 768;  dst = wbf + 589824 + 4718592 + lw; K = 3072; N = 768;  }
        bid = t;
    }
    const int tilesN = N / 32;
    const int nt = (bid % tilesN) * 32, kt = (bid / tilesN) * 32;

    __shared__ ushort_t tl[32][33];
    const int tx = threadIdx.x & 31, ty = threadIdx.x >> 5;  // ty 0..7
#pragma unroll
    for (int r = 0; r < 4; r++) {
        const int k = kt + ty + r * 8;
        tl[ty + r * 8][tx] = f2bf(src[(size_t)k * N + nt + tx]);
    }
    __syncthreads();
#pragma unroll
    for (int r = 0; r < 4; r++) {
        const int n = nt + ty + r * 8;
        dst[(size_t)n * K + kt + tx] = tl[tx][ty + r * 8];
    }
}

// ---------------------------------------------------------------------------
// LayerNorm over last dim (768). One block (256 thr) per row. OT: float|ushort
// r10 measured the 192-thr/float4 variant at +5 us (launch-rate-bound at
// 8192 tiny blocks; 3-wave blocks pack CU wave slots worse) — r8 scalar
// version restored.
// ---------------------------------------------------------------------------
template <typename OT>
__global__ __launch_bounds__(256) void ln_kernel(const float* in, const float* g, OT* out)
{
    const int row = blockIdx.x;
    const int tid = threadIdx.x;
    const float* rp = in + (size_t)row * DIM;
    float vals[3];
    float s = 0.f, s2 = 0.f;
#pragma unroll
    for (int k = 0; k < 3; k++) {
        float v = rp[tid + k * 256];
        vals[k] = v;
        s += v; s2 += v * v;
    }
#pragma unroll
    for (int o = 32; o; o >>= 1) {
        s  += __shfl_xor(s, o);
        s2 += __shfl_xor(s2, o);
    }
    __shared__ float red[8];
    const int wid = tid >> 6;
    if ((tid & 63) == 0) { red[wid] = s; red[wid + 4] = s2; }
    __syncthreads();
    s  = red[0] + red[1] + red[2] + red[3];
    s2 = red[4] + red[5] + red[6] + red[7];
    const float mean = s * (1.f / DIM);
    const float var  = s2 * (1.f / DIM) - mean * mean;
    const float inv  = rsqrtf(var + 1e-5f);
    OT* op = out + (size_t)row * DIM;
#pragma unroll
    for (int k = 0; k < 3; k++) {
        const float v = (vals[k] - mean) * inv * g[tid + k * 256];
        if constexpr (sizeof(OT) == 2) op[tid + k * 256] = f2bf(v);
        else                           op[tid + k * 256] = v;
    }
}

// ---------------------------------------------------------------------------
// BF16 MFMA GEMM: C[M,N] = act(A[M,K] @ Bt[N,K]^T + bias) + resid
// TM x 128 tile, BK=64, 256 thr = 4 waves (2x2), 16x16x32 MFMA.
// Staging swizzle: 8 lanes/row (128B), chunk ^= row&7 -> conflict-free
// fragment reads (SQ_LDS_BANK_CONFLICT = 0 measured).
// Structure: dbuf + counted s_waitcnt vmcnt(NL) + raw s_barrier (T3+T4).
// TM RULE (r4 + r9, twice-measured): grid EVENNESS dominates staging
// intensity. N=768 outputs MUST be TM=64 (768 blocks = 3/CU even); TM=128
// gives 384 blocks -> 2-vs-1 blocks/CU makespan loss. TM=128 only where
// grid >= ~4 blocks/CU: QKV (1152 blk), W1 (1536 blk).
// ---------------------------------------------------------------------------
template <int TM>
__global__ __launch_bounds__(256) void gemm_bf(
    const ushort_t* __restrict__ A, const ushort_t* __restrict__ Bt,
    const float* __restrict__ bias, const float* __restrict__ resid,
    void* __restrict__ Cv, int M, int N, int K, int outbf, int act)
{
    constexpr int MF = TM / 32;  // m-frags per wave: 4 (TM=128) or 2 (TM=64)
    constexpr int AG = TM / 32;  // A staging groups of 32 rows
    __shared__ ushort_t As[2][TM * 64];
    __shared__ ushort_t Bs[2][128 * 64];
    const int tid  = threadIdx.x;
    const int w    = tid >> 6, lane = tid & 63;
    const int lq   = lane & 15, quad = lane >> 4;
    const int wm   = w & 1, wn = w >> 1;
    const int tileM = blockIdx.y * TM, tileN = blockIdx.x * 128;

    const int srow   = lane >> 3;                 // 0..7
    const int schunk = (lane & 7) ^ srow;         // swizzled k-chunk (8 ushorts)
    const ushort_t* agp[AG];
    const ushort_t* bgp[4];
#pragma unroll
    for (int g = 0; g < AG; g++)
        agp[g] = A + (size_t)(tileM + g * 32 + w * 8 + srow) * K + schunk * 8;
#pragma unroll
    for (int g = 0; g < 4; g++)
        bgp[g] = Bt + (size_t)(tileN + g * 32 + w * 8 + srow) * K + schunk * 8;

    f32x4 acc[MF][4];
#pragma unroll
    for (int m = 0; m < MF; m++)
#pragma unroll
        for (int n = 0; n < 4; n++) acc[m][n] = (f32x4){0.f, 0.f, 0.f, 0.f};

    const int fsw0 = (quad ^ (lq & 7)) * 8;
    const int fsw1 = ((quad ^ (lq & 7)) ^ 4) * 8;

#pragma unroll
    for (int g = 0; g < AG; g++)
        gld16(agp[g], As[0] + (g * 32 + w * 8) * 64);
#pragma unroll
    for (int g = 0; g < 4; g++)
        gld16(bgp[g], Bs[0] + (g * 32 + w * 8) * 64);

    int buf = 0;
    for (int kt = 0; kt < K; kt += 64, buf ^= 1) {
        if (kt + 64 < K) {
#pragma unroll
            for (int g = 0; g < AG; g++)
                gld16(agp[g] + kt + 64, As[buf ^ 1] + (g * 32 + w * 8) * 64);
#pragma unroll
            for (int g = 0; g < 4; g++)
                gld16(bgp[g] + kt + 64, Bs[buf ^ 1] + (g * 32 + w * 8) * 64);
            if constexpr (TM == 128) asm volatile("s_waitcnt vmcnt(8)" ::: "memory");
            else                     asm volatile("s_waitcnt vmcnt(6)" ::: "memory");
        } else {
            asm volatile("s_waitcnt vmcnt(0)" ::: "memory");
        }
        __builtin_amdgcn_s_barrier();

        bf16x8 af0[MF], af1[MF], bf0[4], bf1[4];
#pragma unroll
        for (int m = 0; m < MF; m++) {
            const int base = ((wm * MF + m) * 16 + lq) * 64;
            af0[m] = *(const bf16x8*)&As[buf][base + fsw0];
            af1[m] = *(const bf16x8*)&As[buf][base + fsw1];
        }
#pragma unroll
        for (int n = 0; n < 4; n++) {
            const int base = ((wn * 4 + n) * 16 + lq) * 64;
            bf0[n] = *(const bf16x8*)&Bs[buf][base + fsw0];
            bf1[n] = *(const bf16x8*)&Bs[buf][base + fsw1];
        }
#pragma unroll
        for (int n = 0; n < 4; n++)
#pragma unroll
            for (int m = 0; m < MF; m++) {
                acc[m][n] = __builtin_amdgcn_mfma_f32_16x16x32_bf16(af0[m], bf0[n], acc[m][n], 0, 0, 0);
                acc[m][n] = __builtin_amdgcn_mfma_f32_16x16x32_bf16(af1[m], bf1[n], acc[m][n], 0, 0, 0);
            }
        __builtin_amdgcn_s_barrier();
    }

    float* Cf = (float*)Cv;
    ushort_t* Cb = (ushort_t*)Cv;
#pragma unroll
    for (int m = 0; m < MF; m++) {
#pragma unroll
        for (int n = 0; n < 4; n++) {
            const int col = tileN + wn * 64 + n * 16 + lq;
            const float bv = bias ? bias[col] : 0.f;
#pragma unroll
            for (int r = 0; r < 4; r++) {
                const int row = tileM + wm * (TM / 2) + m * 16 + quad * 4 + r;
                float v = acc[m][n][r] + bv;
                if (act) v = gelu_f(v);
                const size_t off = (size_t)row * N + col;
                if (resid) v += resid[off];
                if (outbf) Cb[off] = f2bf(v);
                else       Cf[off] = v;
            }
        }
    }
}

// ---------------------------------------------------------------------------
// QKV GEMM with FUSED RMS-norm + 2D-RoPE epilogue (r11). Replaces the
// separate rmsrope kernel (49152-block launch + 50 MB q|k round-trip, x2
// layers). Main loop = gemm_bf<128> body. Key geometry: tileN and wn*64 are
// 64-aligned and DH=64, so each wave's 64-col span is EXACTLY one head:
//   cols [0,768) = q heads, [768,1536) = k heads, [1536,2304) = v (plain).
// Per output row, RMS sum-of-squares = 4 in-thread squares (n=0..3) +
// shfl_xor{1,2,4,8} over the 16 lq lanes (same rows, different cols).
// RoPE partner col +-16 = accumulator n^1 of the SAME thread; d&15 = lq;
// half (d<32) = (n<2) -> h_idx, else w_idx. Norm runs on fp32 accumulators
// (better than the old bf16 round-trip). Scale 8 = sqrt(DH).
// ---------------------------------------------------------------------------
__global__ __launch_bounds__(256) void gemm_qkv_kernel(
    const ushort_t* __restrict__ A, const ushort_t* __restrict__ Bt,
    ushort_t* __restrict__ C, const float* __restrict__ qg,
    const float* __restrict__ kg, const int* __restrict__ h_idx,
    const int* __restrict__ w_idx, int M, int N, int K)
{
    constexpr int TM = 128;
    constexpr int MF = 4;
    constexpr int AG = 4;
    __shared__ ushort_t As[2][TM * 64];
    __shared__ ushort_t Bs[2][128 * 64];
    const int tid  = threadIdx.x;
    const int w    = tid >> 6, lane = tid & 63;
    const int lq   = lane & 15, quad = lane >> 4;
    const int wm   = w & 1, wn = w >> 1;
    const int tileM = blockIdx.y * TM, tileN = blockIdx.x * 128;

    const int srow   = lane >> 3;
    const int schunk = (lane & 7) ^ srow;
    const ushort_t* agp[AG];
    const ushort_t* bgp[4];
#pragma unroll
    for (int g = 0; g < AG; g++)
        agp[g] = A + (size_t)(tileM + g * 32 + w * 8 + srow) * K + schunk * 8;
#pragma unroll
    for (int g = 0; g < 4; g++)
        bgp[g] = Bt + (size_t)(tileN + g * 32 + w * 8 + srow) * K + schunk * 8;

    f32x4 acc[MF][4];
#pragma unroll
    for (int m = 0; m < MF; m++)
#pragma unroll
        for (int n = 0; n < 4; n++) acc[m][n] = (f32x4){0.f, 0.f, 0.f, 0.f};

    const int fsw0 = (quad ^ (lq & 7)) * 8;
    const int fsw1 = ((quad ^ (lq & 7)) ^ 4) * 8;

#pragma unroll
    for (int g = 0; g < AG; g++)
        gld16(agp[g], As[0] + (g * 32 + w * 8) * 64);
#pragma unroll
    for (int g = 0; g < 4; g++)
        gld16(bgp[g], Bs[0] + (g * 32 + w * 8) * 64);

    int buf = 0;
    for (int kt = 0; kt < K; kt += 64, buf ^= 1) {
        if (kt + 64 < K) {
#pragma unroll
            for (int g = 0; g < AG; g++)
                gld16(agp[g] + kt + 64, As[buf ^ 1] + (g * 32 + w * 8) * 64);
#pragma unroll
            for (int g = 0; g < 4; g++)
                gld16(bgp[g] + kt + 64, Bs[buf ^ 1] + (g * 32 + w * 8) * 64);
            asm volatile("s_waitcnt vmcnt(8)" ::: "memory");
        } else {
            asm volatile("s_waitcnt vmcnt(0)" ::: "memory");
        }
        __builtin_amdgcn_s_barrier();

        bf16x8 af0[MF], af1[MF], bf0[4], bf1[4];
#pragma unroll
        for (int m = 0; m < MF; m++) {
            const int base = ((wm * MF + m) * 16 + lq) * 64;
            af0[m] = *(const bf16x8*)&As[buf][base + fsw0];
            af1[m] = *(const bf16x8*)&As[buf][base + fsw1];
        }
#pragma unroll
        for (int n = 0; n < 4; n++) {
            const int base = ((wn * 4 + n) * 16 + lq) * 64;
            bf0[n] = *(const bf16x8*)&Bs[buf][base + fsw0];
            bf1[n] = *(const bf16x8*)&Bs[buf][base + fsw1];
        }
#pragma unroll
        for (int n = 0; n < 4; n++)
#pragma unroll
            for (int m = 0; m < MF; m++) {
                acc[m][n] = __builtin_amdgcn_mfma_f32_16x16x32_bf16(af0[m], bf0[n], acc[m][n], 0, 0, 0);
                acc[m][n] = __builtin_amdgcn_mfma_f32_16x16x32_bf16(af1[m], bf1[n], acc[m][n], 0, 0, 0);
            }
        __builtin_amdgcn_s_barrier();
    }

    const int colb = tileN + wn * 64;   // 64-aligned -> one head per wave
    if (colb >= 2 * DIM) {
        // ---- v region: plain bf16 store ----
#pragma unroll
        for (int m = 0; m < MF; m++)
#pragma unroll
            for (int n = 0; n < 4; n++) {
                const int col = colb + n * 16 + lq;
#pragma unroll
                for (int r = 0; r < 4; r++) {
                    const int row = tileM + wm * 64 + m * 16 + quad * 4 + r;
                    C[(size_t)row * N + col] = f2bf(acc[m][n][r]);
                }
            }
        return;
    }

    // ---- q/k region: RMS-norm over head (64 cols) + 2D RoPE, then store ----
    const float* gq = (colb < DIM) ? (qg + colb) : (kg + (colb - DIM));
    float gv4[4];
#pragma unroll
    for (int n = 0; n < 4; n++) gv4[n] = gq[n * 16 + lq];
    // 10000^(-lq/16) = exp2(-lq * log2(10000)/16)
    const float freq = exp2f((float)lq * -0.8304820237218407f);

#pragma unroll
    for (int m = 0; m < MF; m++) {
#pragma unroll
        for (int r = 0; r < 4; r++) {
            const int row = tileM + wm * 64 + m * 16 + quad * 4 + r;
            float v0 = acc[m][0][r], v1 = acc[m][1][r];
            float v2 = acc[m][2][r], v3 = acc[m][3][r];
            float ss = (v0 * v0 + v1 * v1) + (v2 * v2 + v3 * v3);
            ss += __shfl_xor(ss, 1);
            ss += __shfl_xor(ss, 2);
            ss += __shfl_xor(ss, 4);
            ss += __shfl_xor(ss, 8);
            const float sc = 8.0f / fmaxf(sqrtf(ss), 1e-12f);
            v0 *= sc * gv4[0]; v1 *= sc * gv4[1];
            v2 *= sc * gv4[2]; v3 *= sc * gv4[3];
            const float th1 = (float)h_idx[row] * freq;   // cols [0,32): n=0,1
            const float th2 = (float)w_idx[row] * freq;   // cols [32,64): n=2,3
            const float s1 = __sinf(th1), c1 = __cosf(th1);
            const float s2 = __sinf(th2), c2 = __cosf(th2);
            const float o0 = v0 * c1 - v1 * s1;
            const float o1 = v1 * c1 + v0 * s1;
            const float o2 = v2 * c2 - v3 * s2;
            const float o3 = v3 * c2 + v2 * s2;
            const size_t off = (size_t)row * N + colb + lq;
            C[off]      = f2bf(o0);
            C[off + 16] = f2bf(o1);
            C[off + 32] = f2bf(o2);
            C[off + 48] = f2bf(o3);
        }
    }
}

// ---------------------------------------------------------------------------
// V transpose: qkv v-block [B,N,H,DH] -> Vt [B,H,DH,N] bf16. 32x32 LDS tiles.
// ---------------------------------------------------------------------------
__global__ __launch_bounds__(256) void vtrans_kernel(
    const ushort_t* __restrict__ QKV, ushort_t* __restrict__ Vt)
{
    __shared__ ushort_t t[32][33];
    const int bh = blockIdx.x;
    const int b = bh / NH, h = bh % NH;
    const int d0 = blockIdx.y * 32, n0 = blockIdx.z * 32;
    const int tx = threadIdx.x & 31, ty = threadIdx.x >> 5;
#pragma unroll
    for (int r = 0; r < 4; r++) {
        const int n = n0 + ty + r * 8;
        t[ty + r * 8][tx] = QKV[(size_t)(b * NN + n) * QKVD + 2 * DIM + h * DH + d0 + tx];
    }
    __syncthreads();
#pragma unroll
    for (int r = 0; r < 4; r++) {
        const int d = d0 + ty + r * 8;
        Vt[((size_t)(b * NH + h) * DH + d) * NN + n0 + tx] = t[tx][ty + r * 8];
    }
}

// ---------------------------------------------------------------------------
// BF16 MFMA flash attention — r0-EXACT body (measured 91.2-93.1 us).
// Streaming softmax (fixed max = 0; QK-RMSNorm bounds |s| <= 64). Block =
// 4 waves, 64 queries (16/wave). grid (B*H, N/64): wgid%8 == bh%8 -> K/V
// L2-resident per XCD (FETCH 14 MB). Ps stride 76 (152 B): start bank 6*lq
// walks all 16 even banks -> 8.45M conflict cyc (vs 14.79M @ 80).
// r1-r5 micro-variants (queue, setprio, exp2-fold, cvt_pk, tail-split) all
// measured neutral-to-negative; body is locked.
// ---------------------------------------------------------------------------
__global__ __launch_bounds__(256) void attn_kernel(
    const ushort_t* __restrict__ QKV, const ushort_t* __restrict__ Vt_g,
    const int* __restrict__ lengths, ushort_t* __restrict__ O)
{
    __shared__ ushort_t Ks[64 * 64];
    __shared__ ushort_t Vs[64 * 64];
    __shared__ ushort_t Ps[4][16][76];

    const int bh = blockIdx.x;
    const int b  = bh / NH;
    const int h  = bh % NH;
    const int qbase = blockIdx.y * 64;
    const int tid  = threadIdx.x;
    const int w    = tid >> 6;
    const int lane = tid & 63;
    const int lq   = lane & 15;
    const int quad = lane >> 4;
    const int len  = lengths[b];

    const int qrow = qbase + w * 16 + lq;
    const ushort_t* qp = QKV + (size_t)(b * NN + qrow) * QKVD + h * DH + quad * 8;
    bf16x8 aq0 = *(const bf16x8*)(qp);
    bf16x8 aq1 = *(const bf16x8*)(qp + 32);

    const int e0 = tid, e1 = tid + 256;
    const int r0 = e0 >> 3, c80 = e0 & 7;
    const int r1 = e1 >> 3, c81 = e1 & 7;
    const int g0 = (c80 ^ (r0 & 7) ^ (r0 >> 3)) & 7;
    const int g1 = (c81 ^ (r1 & 7) ^ (r1 >> 3)) & 7;
    const ushort_t* kg0 = QKV + (size_t)(b * NN + r0) * QKVD + DIM + h * DH + g0 * 8;
    const ushort_t* kg1 = QKV + (size_t)(b * NN + r1) * QKVD + DIM + h * DH + g1 * 8;
    const ushort_t* vg0 = Vt_g + ((size_t)(b * NH + h) * DH + r0) * NN + g0 * 8;
    const ushort_t* vg1 = Vt_g + ((size_t)(b * NH + h) * DH + r1) * NN + g1 * 8;
    ushort_t* kl0 = Ks + (w * 64) * 8;
    ushort_t* kl1 = Ks + (256 + w * 64) * 8;
    ushort_t* vl0 = Vs + (w * 64) * 8;
    ushort_t* vl1 = Vs + (256 + w * 64) * 8;

    f32x4 oacc[4];
#pragma unroll
    for (int t4 = 0; t4 < 4; t4++) oacc[t4] = (f32x4){0.f, 0.f, 0.f, 0.f};
    float lsum = 0.f;

    const int ntiles = (len + 63) >> 6;
    for (int t = 0; t < ntiles; t++) {
        const int j0 = t * 64;
        gld16(kg0 + (size_t)j0 * QKVD, kl0);
        gld16(kg1 + (size_t)j0 * QKVD, kl1);
        gld16(vg0 + j0, vl0);
        gld16(vg1 + j0, vl1);
        __syncthreads();

        f32x4 s[4];
#pragma unroll
        for (int n = 0; n < 4; n++) {
            const int krow = n * 16 + lq;
            const int hashk = (krow & 7) ^ (krow >> 3);
            bf16x8 ak0 = *(const bf16x8*)&Ks[(krow * 8 + ((quad ^ hashk) & 7)) * 8];
            bf16x8 ak1 = *(const bf16x8*)&Ks[(krow * 8 + (((quad + 4) ^ hashk) & 7)) * 8];
            f32x4 acc = (f32x4){0.f, 0.f, 0.f, 0.f};
            acc = __builtin_amdgcn_mfma_f32_16x16x32_bf16(ak0, aq0, acc, 0, 0, 0);
            acc = __builtin_amdgcn_mfma_f32_16x16x32_bf16(ak1, aq1, acc, 0, 0, 0);
            s[n] = acc;
        }

        float p[4][4];
#pragma unroll
        for (int n = 0; n < 4; n++) {
            const int keyb = j0 + n * 16 + quad * 4;
#pragma unroll
            for (int r = 0; r < 4; r++) {
                float pv = __expf(s[n][r]);
                pv = (keyb + r < len) ? pv : 0.f;
                p[n][r] = pv;
                lsum += pv;
            }
        }

#pragma unroll
        for (int n = 0; n < 4; n++) {
            const unsigned lo = (unsigned)f2bf(p[n][0]) | ((unsigned)f2bf(p[n][1]) << 16);
            const unsigned hi = (unsigned)f2bf(p[n][2]) | ((unsigned)f2bf(p[n][3]) << 16);
            *(uint2*)&Ps[w][lq][n * 16 + quad * 4] = make_uint2(lo, hi);
        }
        asm volatile("s_waitcnt lgkmcnt(0)" ::: "memory");
        bf16x8 ap0 = *(const bf16x8*)&Ps[w][lq][quad * 8];
        bf16x8 ap1 = *(const bf16x8*)&Ps[w][lq][32 + quad * 8];

#pragma unroll
        for (int t4 = 0; t4 < 4; t4++) {
            const int vrow = t4 * 16 + lq;
            const int hashv = (vrow & 7) ^ (vrow >> 3);
            bf16x8 bv0 = *(const bf16x8*)&Vs[(vrow * 8 + ((quad ^ hashv) & 7)) * 8];
            bf16x8 bv1 = *(const bf16x8*)&Vs[(vrow * 8 + (((quad + 4) ^ hashv) & 7)) * 8];
            oacc[t4] = __builtin_amdgcn_mfma_f32_16x16x32_bf16(ap0, bv0, oacc[t4], 0, 0, 0);
            oacc[t4] = __builtin_amdgcn_mfma_f32_16x16x32_bf16(ap1, bv1, oacc[t4], 0, 0, 0);
        }
        __syncthreads();
    }

    lsum += __shfl_xor(lsum, 16);
    lsum += __shfl_xor(lsum, 32);
    float invq[4];
#pragma unroll
    for (int r = 0; r < 4; r++) invq[r] = 1.f / __shfl(lsum, quad * 4 + r);

#pragma unroll
    for (int t4 = 0; t4 < 4; t4++) {
#pragma unroll
        for (int r = 0; r < 4; r++) {
            const int qr = qbase + w * 16 + quad * 4 + r;
            O[((size_t)(b * NN + qr)) * DIM + h * DH + t4 * 16 + lq] = f2bf(oacc[t4][r] * invq[r]);
        }
    }
}

// ---------------------------------------------------------------------------
__global__ __launch_bounds__(256) void mask_kernel(const int* __restrict__ lengths, float* __restrict__ out)
{
    const int i = blockIdx.x * 256 + threadIdx.x;
    const int b = i >> 11;
    const int n = i & (NN - 1);
    out[i] = (n < lengths[b]) ? 1.f : 0.f;
}

// ---------------------------------------------------------------------------
extern "C" void kernel_launch(void* const* d_in, const int* in_sizes, int n_in,
                              void* d_out, int out_size, void* d_ws, size_t ws_size,
                              hipStream_t stream)
{
    const float* patches    = (const float*)d_in[0];
    const float* pe_ln1_g   = (const float*)d_in[1];
    const float* pe_W       = (const float*)d_in[2];
    const float* pe_b       = (const float*)d_in[3];
    const float* pe_ln2_g   = (const float*)d_in[4];
    const float* attn_ln_g  = (const float*)d_in[5];
    const float* qn_g       = (const float*)d_in[6];
    const float* kn_g       = (const float*)d_in[7];
    const float* Wq         = (const float*)d_in[8];
    const float* Wkv        = (const float*)d_in[9];
    const float* Wo         = (const float*)d_in[10];
    const float* ff_ln_g    = (const float*)d_in[11];
    const float* W1         = (const float*)d_in[12];
    const float* b1         = (const float*)d_in[13];
    const float* W2         = (const float*)d_in[14];
    const float* b2         = (const float*)d_in[15];
    const float* final_ln_g = (const float*)d_in[16];
    const int*   h_idx      = (const int*)d_in[17];
    const int*   w_idx      = (const int*)d_in[18];
    const int*   lengths    = (const int*)d_in[19];

    float* out = (float*)d_out;
    char*  p   = (char*)d_ws;

    const size_t MB = 1024 * 1024;
    ushort_t* wbf = (ushort_t*)p;                       // ~28.1 MiB of bf16 weights
    ushort_t* peWt = wbf;
    size_t woff = (size_t)DIM * DIM;                    // 589824
    ushort_t* Wqkvt[LNUM], *Wot[LNUM], *W1t[LNUM], *W2t[LNUM];
    for (int i = 0; i < LNUM; i++) {
        Wqkvt[i] = wbf + woff; woff += (size_t)QKVD * DIM;  // q rows then kv rows
        Wot[i]   = wbf + woff; woff += (size_t)DIM * DIM;
        W1t[i]   = wbf + woff; woff += (size_t)DIM * MLPD;
        W2t[i]   = wbf + woff; woff += (size_t)MLPD * DIM;
    }
    ushort_t* xnbf = (ushort_t*)(p + 30 * MB);          // [8192,768]  12.6 MB
    ushort_t* qkv  = (ushort_t*)(p + 43 * MB);          // [8192,2304] 37.7 MB
    ushort_t* aob  = (ushort_t*)(p + 82 * MB);          // [8192,768]  12.6 MB
    ushort_t* hb   = (ushort_t*)(p + 43 * MB);          // [8192,3072] 50.3 MB (qkv dead)
    float*    peF  = (float*)(p + 43 * MB);             // [8192,768] fp32 (pe only)
    ushort_t* vtg  = (ushort_t*)(p + 96 * MB);          // [B,H,DH,N]  12.6 MB

    const int ROWS = BB * NN;  // 8192
    dim3 blk(256);

    // ---- ALL weight converts in one launch (14400 tiles) ----
    wconvert_all_kernel<<<dim3(576 + LNUM * 6912), blk, 0, stream>>>(
        pe_W, Wq, Wkv, Wo, W1, W2, wbf);

    // ---- patch embedding: LN -> GEMM(+bias) -> LN ----
    ln_kernel<ushort_t><<<ROWS, blk, 0, stream>>>(patches, pe_ln1_g, xnbf);
    gemm_bf<64><<<dim3(DIM / 128, ROWS / 64), blk, 0, stream>>>(
        xnbf, peWt, pe_b, nullptr, peF, ROWS, DIM, DIM, 0, 0);
    ln_kernel<float><<<ROWS, blk, 0, stream>>>(peF, pe_ln2_g, out);

    float* x = out;  // residual stream lives in d_out
    for (int i = 0; i < LNUM; i++) {
        ln_kernel<ushort_t><<<ROWS, blk, 0, stream>>>(x, attn_ln_g + i * DIM, xnbf);
        // r11: QKV GEMM with fused RMS+RoPE epilogue (rmsrope kernel deleted)
        gemm_qkv_kernel<<<dim3(QKVD / 128, ROWS / 128), blk, 0, stream>>>(
            xnbf, Wqkvt[i], qkv, qn_g + i * NH * DH, kn_g + i * NH * DH,
            h_idx, w_idx, ROWS, QKVD, DIM);
        vtrans_kernel<<<dim3(BB * NH, DH / 32, NN / 32), blk, 0, stream>>>(qkv, vtg);
        attn_kernel<<<dim3(BB * NH, NN / 64), blk, 0, stream>>>(
            qkv, vtg, lengths, aob);
        gemm_bf<64><<<dim3(DIM / 128, ROWS / 64), blk, 0, stream>>>(
            aob, Wot[i], nullptr, x, x, ROWS, DIM, DIM, 0, 0);
        ln_kernel<ushort_t><<<ROWS, blk, 0, stream>>>(x, ff_ln_g + i * DIM, xnbf);
        gemm_bf<128><<<dim3(MLPD / 128, ROWS / 128), blk, 0, stream>>>(
            xnbf, W1t[i], b1 + i * MLPD, nullptr, hb, ROWS, MLPD, DIM, 1, 1);
        gemm_bf<64><<<dim3(DIM / 128, ROWS / 64), blk, 0, stream>>>(
            hb, W2t[i], b2 + i * DIM, x, x, ROWS, DIM, MLPD, 0, 0);
    }
    ln_kernel<float><<<ROWS, blk, 0, stream>>>(x, final_ln_g, out);
    mask_kernel<<<ROWS / 256, blk, 0, stream>>>(lengths, out + (size_t)ROWS * DIM);
}